// Round 15
// baseline (160.932 us; speedup 1.0000x reference)
//
#include <hip/hip_runtime.h>
#include <hip/hip_fp16.h>

// Problem constants
#define BB 2
#define CC 64
#define KK 27
#define S_TOT 32768  // 32^3
#define BN_EPS 1e-5f

// ws layout: xT[2][32768][64] floats (16.8 MB).
#define XT_FLOATS ((size_t)BB * S_TOT * CC)

// ---------------------------------------------------------------------------
// K1: transpose x[b][c][s] -> xT[b][s][c]  (LDS-tiled, proven since R5).
// ---------------------------------------------------------------------------
__global__ __launch_bounds__(256) void xpose_kernel(const float* __restrict__ x,
                                                    float* __restrict__ xT) {
  __shared__ float t[64 * 65];
  const int tid = threadIdx.x;
  const int blk = blockIdx.x;
  const int b   = blk >> 9;
  const int s0  = (blk & 511) << 6;
  const float* xb = x + ((size_t)b << 21);
  {
    const int cq = tid >> 4;
    const int sq = (tid & 15) << 2;
#pragma unroll
    for (int i = 0; i < 4; ++i) {
      int c = cq + (i << 4);
      float4 v = *(const float4*)(xb + ((size_t)c << 15) + s0 + sq);
      t[c * 65 + sq + 0] = v.x;
      t[c * 65 + sq + 1] = v.y;
      t[c * 65 + sq + 2] = v.z;
      t[c * 65 + sq + 3] = v.w;
    }
  }
  __syncthreads();
  {
    float* xTb = xT + ((size_t)b << 21);
    const int si = tid >> 2;
    const int cb = (tid & 3) << 4;
#pragma unroll
    for (int j = 0; j < 4; ++j) {
      int c = cb + (j << 2);
      float4 w;
      w.x = t[(c + 0) * 65 + si];
      w.y = t[(c + 1) * 65 + si];
      w.z = t[(c + 2) * 65 + si];
      w.w = t[(c + 3) * 65 + si];
      *(float4*)(xTb + ((size_t)(s0 + si) << 6) + c) = w;
    }
  }
}

// ---------------------------------------------------------------------------
// K2: FUSED kergen + gather — R12 base (2048 x 256-thread blocks, p-split;
// measured 122us / VGPR 64 / 42.6% occ). R14's 512-thread merge LOST
// residency (31.8% occ, 153us) — reverted. This round's two edits:
//   (a) sv fp16: LDS 33.8 -> 24.9 KB -> 6 blocks/CU (75% occupancy ceiling)
//   (b) gather unroll 3 (was 2): 6 loads in flight; VGPR ~75 under the
//       (256,6) budget of 85 — slack kept per R13 lesson (never cap at
//       the natural value).
// Block (b, p, tile), 4 waves; wave w owns group g = 4p + w; lane si owns
// spatial column s0+si. kl[w][j][si] written & read by the SAME thread ->
// single barrier in the kernel (covers sv + offs).
// ---------------------------------------------------------------------------
__global__ __launch_bounds__(256, 6) void invol_fused_xt(
    const float* __restrict__ xT, const float* __restrict__ wr,
    const float* __restrict__ wsp, const float* __restrict__ gamma,
    const float* __restrict__ beta, const float* __restrict__ mean,
    const float* __restrict__ var, float* __restrict__ out) {
  __shared__ __half sv[CC * 64];             // 8 KB
  __shared__ __half kl[4 * KK * 64];         // 13.5 KB
  __shared__ unsigned short offs[KK * 64];   // 3.375 KB   -> total 24.9 KB

  const int tid = threadIdx.x;
  const int blk = blockIdx.x;
  const int b   = blk >> 10;
  const int p   = (blk >> 9) & 1;
  const int s0  = (blk & 511) << 6;
  const int si  = tid & 63;
  const int w   = __builtin_amdgcn_readfirstlane(tid >> 6);  // wave 0..3
  const int g   = (p << 2) + w;                               // group 0..7
  const int c0  = g << 3;

  // ---- Phase 0: offset table ----
  // f = k*32768 + s, mixed radix [od:32][oh:32][ow:32][kd:3][kh:3][kw:3];
  // (dd,hh,ww) = (od+kd-1, oh+kh-1, ow+kw-1); 0xFFFF if OOB (zero pad).
  for (int i = tid; i < KK * 64; i += 256) {
    int k  = i >> 6;
    int f  = (k << 15) + s0 + (i & 63);
    int kw = f % 3; int u = f / 3;
    int kh = u % 3; u /= 3;
    int kd = u % 3; u /= 3;
    int ww = (u & 31) + kw - 1; u >>= 5;
    int hh = (u & 31) + kh - 1; u >>= 5;
    int dd = u + kd - 1;
    unsigned short off = 0xFFFFu;
    if (((unsigned)ww < 32u) & ((unsigned)hh < 32u) & ((unsigned)dd < 32u))
      off = (unsigned short)((dd << 10) + (hh << 5) + ww);
    offs[i] = off;
  }

  // ---- Phase 1: GEMM1 + BN + ReLU -> sv fp16 (16 channels per wave) ----
  {
    const float* xrow = xT + ((((size_t)b << 15) + s0 + si) << 6);  // xT[b][s][*]
    float acc[16];
#pragma unroll
    for (int j = 0; j < 16; ++j) acc[j] = 0.f;
#pragma unroll
    for (int half = 0; half < 2; ++half) {
      float xv[32];
#pragma unroll
      for (int q = 0; q < 8; ++q) {
        float4 v = *(const float4*)(xrow + half * 32 + q * 4);
        xv[q * 4 + 0] = v.x;
        xv[q * 4 + 1] = v.y;
        xv[q * 4 + 2] = v.z;
        xv[q * 4 + 3] = v.w;
      }
      const float* wrw = wr + (w * 16) * CC + half * 32;
#pragma unroll
      for (int j = 0; j < 16; ++j) {
        const float* r0 = wrw + j * CC;
        float a0 = 0.f, a1 = 0.f;
#pragma unroll
        for (int c = 0; c < 32; c += 2) {
          a0 = fmaf(r0[c],     xv[c],     a0);
          a1 = fmaf(r0[c + 1], xv[c + 1], a1);
        }
        acc[j] += a0 + a1;
      }
    }
#pragma unroll
    for (int j = 0; j < 16; ++j) {
      int o = w * 16 + j;
      float v = (acc[j] - mean[o]) * rsqrtf(var[o] + BN_EPS) * gamma[o] + beta[o];
      sv[o * 64 + si] = __float2half(v > 0.f ? v : 0.f);
    }
  }
  __syncthreads();  // covers sv + offs (only barrier in the kernel)

  // ---- Phase 2: GEMM2 -> kl (fp16 LDS), runtime jt chunk loop ----
  {
    __half* klw = kl + (w * KK) * 64 + si;
#pragma unroll 1
    for (int jt = 0; jt < 3; ++jt) {
      float acc[9];
#pragma unroll
      for (int j = 0; j < 9; ++j) acc[j] = 0.f;
      const float* wsb = wsp + (g * KK + jt * 9) * CC;
#pragma unroll
      for (int e = 0; e < 8; ++e) {
        float xv[8];
#pragma unroll
        for (int c = 0; c < 8; ++c)
          xv[c] = __half2float(sv[(e * 8 + c) * 64 + si]);
        const float* wsw = wsb + e * 8;
#pragma unroll
        for (int j = 0; j < 9; ++j) {
          const float* r = wsw + j * CC;
          float a0 = 0.f, a1 = 0.f;
#pragma unroll
          for (int c = 0; c < 8; c += 2) {
            a0 = fmaf(r[c],     xv[c],     a0);
            a1 = fmaf(r[c + 1], xv[c + 1], a1);
          }
          acc[j] += a0 + a1;
        }
      }
      __half* klt = klw + jt * 9 * 64;
#pragma unroll
      for (int j = 0; j < 9; ++j)
        klt[j * 64] = __float2half(acc[j]);
    }
  }
  // no barrier: kl[w][*][si] written and read by the SAME thread.

  // ---- Phase 3: gather-reduce from xT (rolled k-loop, unroll 3) ----
  {
    const float* xTb = xT + ((size_t)b << 21) + c0;
    const __half* klr = kl + (w * KK) * 64 + si;
    float oacc[8];
#pragma unroll
    for (int i = 0; i < 8; ++i) oacc[i] = 0.f;

#pragma unroll 3
    for (int k = 0; k < KK; ++k) {
      unsigned off = offs[(k << 6) + si];
      float kvr = __half2float(klr[k * 64]);
      float kv  = (off != 0xFFFFu) ? kvr : 0.f;
      unsigned o2 = (off != 0xFFFFu) ? off : 0u;
      const float* xp = xTb + ((size_t)o2 << 6);
      float4 v0 = *(const float4*)xp;
      float4 v1 = *(const float4*)(xp + 4);
      oacc[0] = fmaf(kv, v0.x, oacc[0]);
      oacc[1] = fmaf(kv, v0.y, oacc[1]);
      oacc[2] = fmaf(kv, v0.z, oacc[2]);
      oacc[3] = fmaf(kv, v0.w, oacc[3]);
      oacc[4] = fmaf(kv, v1.x, oacc[4]);
      oacc[5] = fmaf(kv, v1.y, oacc[5]);
      oacc[6] = fmaf(kv, v1.z, oacc[6]);
      oacc[7] = fmaf(kv, v1.w, oacc[7]);
    }

    float* ob = out + (((size_t)b * CC + c0) << 15) + s0 + si;
#pragma unroll
    for (int i = 0; i < 8; ++i) ob[(size_t)i << 15] = oacc[i];
  }
}

// ---------------------------------------------------------------------------
// Fallback (ws too small): exact R4 fused kernel — known-good 144 us.
// ---------------------------------------------------------------------------
__global__ __launch_bounds__(256, 8) void invol_fused(
    const float* __restrict__ x, const float* __restrict__ wr,
    const float* __restrict__ wsp, const float* __restrict__ gamma,
    const float* __restrict__ beta, const float* __restrict__ mean,
    const float* __restrict__ var, float* __restrict__ out) {
  __shared__ float sv[CC * 64];
  __shared__ int offs[KK * 64];

  const int tid = threadIdx.x;
  const int blk = blockIdx.x;
  const int b   = blk >> 10;
  const int p   = (blk >> 9) & 1;
  const int s0  = (blk & 511) << 6;
  const int si  = tid & 63;
  const int w   = __builtin_amdgcn_readfirstlane(tid >> 6);
  const int g   = (p << 2) + w;

  const float* xb  = x + ((size_t)b << 21);
  const float* xs0 = xb + s0 + si;

  for (int i = tid; i < KK * 64; i += 256) {
    int k  = i >> 6;
    int f  = (k << 15) + s0 + (i & 63);
    int kw = f % 3; int u = f / 3;
    int kh = u % 3; u /= 3;
    int kd = u % 3; u /= 3;
    int ww = (u & 31) + kw - 1; u >>= 5;
    int hh = (u & 31) + kh - 1; u >>= 5;
    int dd = u + kd - 1;
    int off = -1;
    if (((unsigned)ww < 32u) & ((unsigned)hh < 32u) & ((unsigned)dd < 32u))
      off = (dd << 10) + (hh << 5) + ww;
    offs[i] = off;
  }

  {
    float acc[16];
#pragma unroll
    for (int j = 0; j < 16; ++j) acc[j] = 0.f;
#pragma unroll
    for (int half = 0; half < 2; ++half) {
      float xv[32];
#pragma unroll
      for (int c = 0; c < 32; ++c)
        xv[c] = xs0[(size_t)(half * 32 + c) << 15];
      const float* wrw = wr + (w * 16) * CC + half * 32;
#pragma unroll
      for (int j = 0; j < 16; ++j) {
        const float* r0 = wrw + j * CC;
        float a0 = 0.f, a1 = 0.f;
#pragma unroll
        for (int c = 0; c < 32; c += 2) {
          a0 = fmaf(r0[c],     xv[c],     a0);
          a1 = fmaf(r0[c + 1], xv[c + 1], a1);
        }
        acc[j] += a0 + a1;
      }
    }
#pragma unroll
    for (int j = 0; j < 16; ++j) {
      int o = w * 16 + j;
      float v = (acc[j] - mean[o]) * rsqrtf(var[o] + BN_EPS) * gamma[o] + beta[o];
      sv[o * 64 + si] = v > 0.f ? v : 0.f;
    }
  }
  __syncthreads();

  float kreg[27];
#pragma unroll
  for (int j = 0; j < KK; ++j) kreg[j] = 0.f;
#pragma unroll
  for (int e = 0; e < 8; ++e) {
    float xv[8];
#pragma unroll
    for (int c = 0; c < 8; ++c) xv[c] = sv[(e * 8 + c) * 64 + si];
    const float* wsw = wsp + (g * KK) * CC + e * 8;
#pragma unroll
    for (int j = 0; j < KK; ++j) {
      const float* r = wsw + j * CC;
      float a0 = 0.f, a1 = 0.f;
#pragma unroll
      for (int c = 0; c < 8; c += 2) {
        a0 = fmaf(r[c],     xv[c],     a0);
        a1 = fmaf(r[c + 1], xv[c + 1], a1);
      }
      kreg[j] += a0 + a1;
    }
  }

  {
    const int c0 = g << 3;
    const float* xc0 = xb + ((size_t)c0 << 15);
    float oacc[8];
#pragma unroll
    for (int i = 0; i < 8; ++i) oacc[i] = 0.f;
#pragma unroll
    for (int k = 0; k < KK; ++k) {
      int off = offs[(k << 6) + si];
      float kv = kreg[k];
      if (off >= 0) {
#pragma unroll
        for (int c8 = 0; c8 < 8; ++c8)
          oacc[c8] = fmaf(kv, xc0[off + (c8 << 15)], oacc[c8]);
      }
    }
    float* ob = out + (((size_t)b * CC + c0) << 15) + s0 + si;
#pragma unroll
    for (int i = 0; i < 8; ++i) ob[(size_t)i << 15] = oacc[i];
  }
}

extern "C" void kernel_launch(void* const* d_in, const int* in_sizes, int n_in,
                              void* d_out, int out_size, void* d_ws, size_t ws_size,
                              hipStream_t stream) {
  const float* x     = (const float*)d_in[0];
  const float* wr    = (const float*)d_in[1];
  const float* wsp   = (const float*)d_in[2];
  const float* gamma = (const float*)d_in[3];
  const float* beta  = (const float*)d_in[4];
  const float* mean  = (const float*)d_in[5];
  const float* var   = (const float*)d_in[6];
  float* out = (float*)d_out;

  const size_t need = XT_FLOATS * sizeof(float);  // 16.8 MB
  if (ws_size >= need) {
    float* xT = (float*)d_ws;
    xpose_kernel<<<BB * (S_TOT / 64), 256, 0, stream>>>(x, xT);
    invol_fused_xt<<<BB * 2 * (S_TOT / 64), 256, 0, stream>>>(
        xT, wr, wsp, gamma, beta, mean, var, out);
  } else {
    invol_fused<<<BB * 2 * (S_TOT / 64), 256, 0, stream>>>(
        x, wr, wsp, gamma, beta, mean, var, out);
  }
}

// Round 16
// 126.421 us; speedup vs baseline: 1.2730x; 1.2730x over previous
//
#include <hip/hip_runtime.h>
#include <hip/hip_fp16.h>

// Problem constants
#define BB 2
#define CC 64
#define KK 27
#define S_TOT 32768  // 32^3
#define BN_EPS 1e-5f

// ws layout: xT[2][32768][64] floats (16.8 MB).
#define XT_FLOATS ((size_t)BB * S_TOT * CC)

// ---------------------------------------------------------------------------
// K1: transpose x[b][c][s] -> xT[b][s][c]  (LDS-tiled, proven since R5).
// ---------------------------------------------------------------------------
__global__ __launch_bounds__(256) void xpose_kernel(const float* __restrict__ x,
                                                    float* __restrict__ xT) {
  __shared__ float t[64 * 65];
  const int tid = threadIdx.x;
  const int blk = blockIdx.x;
  const int b   = blk >> 9;
  const int s0  = (blk & 511) << 6;
  const float* xb = x + ((size_t)b << 21);
  {
    const int cq = tid >> 4;
    const int sq = (tid & 15) << 2;
#pragma unroll
    for (int i = 0; i < 4; ++i) {
      int c = cq + (i << 4);
      float4 v = *(const float4*)(xb + ((size_t)c << 15) + s0 + sq);
      t[c * 65 + sq + 0] = v.x;
      t[c * 65 + sq + 1] = v.y;
      t[c * 65 + sq + 2] = v.z;
      t[c * 65 + sq + 3] = v.w;
    }
  }
  __syncthreads();
  {
    float* xTb = xT + ((size_t)b << 21);
    const int si = tid >> 2;
    const int cb = (tid & 3) << 4;
#pragma unroll
    for (int j = 0; j < 4; ++j) {
      int c = cb + (j << 2);
      float4 w;
      w.x = t[(c + 0) * 65 + si];
      w.y = t[(c + 1) * 65 + si];
      w.z = t[(c + 2) * 65 + si];
      w.w = t[(c + 3) * 65 + si];
      *(float4*)(xTb + ((size_t)(s0 + si) << 6) + c) = w;
    }
  }
}

// ---------------------------------------------------------------------------
// K2: FUSED kergen + gather — EXACT R12 structure (2048 x 256-thread blocks,
// p-split, measured 122us / VGPR 64 / zero spill under (256,4) cap-128,
// gather unroll 2) with a SINGLE edit: sv fp32 -> fp16.
//   LDS 33.8 -> 24.9 KB => 6 blocks/CU (was 4): occupancy ceiling 50->75%.
// R15's failure was changing unroll (2->3) AND cap (128->85) together:
// pressure > cap => wholesale array spill (5th incident, same rule).
// Here loop structure and cap are FROZEN; only the LDS footprint shrinks.
// Block (b, p, tile), 4 waves; wave w owns group g = 4p + w; lane si owns
// spatial column s0+si. kl[w][j][si] written & read by the SAME thread ->
// single barrier in the kernel (covers sv + offs).
// ---------------------------------------------------------------------------
__global__ __launch_bounds__(256, 4) void invol_fused_xt(
    const float* __restrict__ xT, const float* __restrict__ wr,
    const float* __restrict__ wsp, const float* __restrict__ gamma,
    const float* __restrict__ beta, const float* __restrict__ mean,
    const float* __restrict__ var, float* __restrict__ out) {
  __shared__ __half sv[CC * 64];             // 8 KB
  __shared__ __half kl[4 * KK * 64];         // 13.5 KB
  __shared__ unsigned short offs[KK * 64];   // 3.375 KB   -> total 24.9 KB

  const int tid = threadIdx.x;
  const int blk = blockIdx.x;
  const int b   = blk >> 10;
  const int p   = (blk >> 9) & 1;
  const int s0  = (blk & 511) << 6;
  const int si  = tid & 63;
  const int w   = __builtin_amdgcn_readfirstlane(tid >> 6);  // wave 0..3
  const int g   = (p << 2) + w;                               // group 0..7
  const int c0  = g << 3;

  // ---- Phase 0: offset table ----
  // f = k*32768 + s, mixed radix [od:32][oh:32][ow:32][kd:3][kh:3][kw:3];
  // (dd,hh,ww) = (od+kd-1, oh+kh-1, ow+kw-1); 0xFFFF if OOB (zero pad).
  for (int i = tid; i < KK * 64; i += 256) {
    int k  = i >> 6;
    int f  = (k << 15) + s0 + (i & 63);
    int kw = f % 3; int u = f / 3;
    int kh = u % 3; u /= 3;
    int kd = u % 3; u /= 3;
    int ww = (u & 31) + kw - 1; u >>= 5;
    int hh = (u & 31) + kh - 1; u >>= 5;
    int dd = u + kd - 1;
    unsigned short off = 0xFFFFu;
    if (((unsigned)ww < 32u) & ((unsigned)hh < 32u) & ((unsigned)dd < 32u))
      off = (unsigned short)((dd << 10) + (hh << 5) + ww);
    offs[i] = off;
  }

  // ---- Phase 1: GEMM1 + BN + ReLU -> sv fp16 (16 channels per wave) ----
  {
    const float* xrow = xT + ((((size_t)b << 15) + s0 + si) << 6);  // xT[b][s][*]
    float acc[16];
#pragma unroll
    for (int j = 0; j < 16; ++j) acc[j] = 0.f;
#pragma unroll
    for (int half = 0; half < 2; ++half) {
      float xv[32];
#pragma unroll
      for (int q = 0; q < 8; ++q) {
        float4 v = *(const float4*)(xrow + half * 32 + q * 4);
        xv[q * 4 + 0] = v.x;
        xv[q * 4 + 1] = v.y;
        xv[q * 4 + 2] = v.z;
        xv[q * 4 + 3] = v.w;
      }
      const float* wrw = wr + (w * 16) * CC + half * 32;
#pragma unroll
      for (int j = 0; j < 16; ++j) {
        const float* r0 = wrw + j * CC;
        float a0 = 0.f, a1 = 0.f;
#pragma unroll
        for (int c = 0; c < 32; c += 2) {
          a0 = fmaf(r0[c],     xv[c],     a0);
          a1 = fmaf(r0[c + 1], xv[c + 1], a1);
        }
        acc[j] += a0 + a1;
      }
    }
#pragma unroll
    for (int j = 0; j < 16; ++j) {
      int o = w * 16 + j;
      float v = (acc[j] - mean[o]) * rsqrtf(var[o] + BN_EPS) * gamma[o] + beta[o];
      sv[o * 64 + si] = __float2half(v > 0.f ? v : 0.f);
    }
  }
  __syncthreads();  // covers sv + offs (only barrier in the kernel)

  // ---- Phase 2: GEMM2 -> kl (fp16 LDS), runtime jt chunk loop ----
  {
    __half* klw = kl + (w * KK) * 64 + si;
#pragma unroll 1
    for (int jt = 0; jt < 3; ++jt) {
      float acc[9];
#pragma unroll
      for (int j = 0; j < 9; ++j) acc[j] = 0.f;
      const float* wsb = wsp + (g * KK + jt * 9) * CC;
#pragma unroll
      for (int e = 0; e < 8; ++e) {
        float xv[8];
#pragma unroll
        for (int c = 0; c < 8; ++c)
          xv[c] = __half2float(sv[(e * 8 + c) * 64 + si]);
        const float* wsw = wsb + e * 8;
#pragma unroll
        for (int j = 0; j < 9; ++j) {
          const float* r = wsw + j * CC;
          float a0 = 0.f, a1 = 0.f;
#pragma unroll
          for (int c = 0; c < 8; c += 2) {
            a0 = fmaf(r[c],     xv[c],     a0);
            a1 = fmaf(r[c + 1], xv[c + 1], a1);
          }
          acc[j] += a0 + a1;
        }
      }
      __half* klt = klw + jt * 9 * 64;
#pragma unroll
      for (int j = 0; j < 9; ++j)
        klt[j * 64] = __float2half(acc[j]);
    }
  }
  // no barrier: kl[w][*][si] written and read by the SAME thread.

  // ---- Phase 3: gather-reduce from xT (rolled k-loop, unroll 2) ----
  {
    const float* xTb = xT + ((size_t)b << 21) + c0;
    const __half* klr = kl + (w * KK) * 64 + si;
    float oacc[8];
#pragma unroll
    for (int i = 0; i < 8; ++i) oacc[i] = 0.f;

#pragma unroll 2
    for (int k = 0; k < KK; ++k) {
      unsigned off = offs[(k << 6) + si];
      float kvr = __half2float(klr[k * 64]);
      float kv  = (off != 0xFFFFu) ? kvr : 0.f;
      unsigned o2 = (off != 0xFFFFu) ? off : 0u;
      const float* xp = xTb + ((size_t)o2 << 6);
      float4 v0 = *(const float4*)xp;
      float4 v1 = *(const float4*)(xp + 4);
      oacc[0] = fmaf(kv, v0.x, oacc[0]);
      oacc[1] = fmaf(kv, v0.y, oacc[1]);
      oacc[2] = fmaf(kv, v0.z, oacc[2]);
      oacc[3] = fmaf(kv, v0.w, oacc[3]);
      oacc[4] = fmaf(kv, v1.x, oacc[4]);
      oacc[5] = fmaf(kv, v1.y, oacc[5]);
      oacc[6] = fmaf(kv, v1.z, oacc[6]);
      oacc[7] = fmaf(kv, v1.w, oacc[7]);
    }

    float* ob = out + (((size_t)b * CC + c0) << 15) + s0 + si;
#pragma unroll
    for (int i = 0; i < 8; ++i) ob[(size_t)i << 15] = oacc[i];
  }
}

// ---------------------------------------------------------------------------
// Fallback (ws too small): exact R4 fused kernel — known-good 144 us.
// ---------------------------------------------------------------------------
__global__ __launch_bounds__(256, 8) void invol_fused(
    const float* __restrict__ x, const float* __restrict__ wr,
    const float* __restrict__ wsp, const float* __restrict__ gamma,
    const float* __restrict__ beta, const float* __restrict__ mean,
    const float* __restrict__ var, float* __restrict__ out) {
  __shared__ float sv[CC * 64];
  __shared__ int offs[KK * 64];

  const int tid = threadIdx.x;
  const int blk = blockIdx.x;
  const int b   = blk >> 10;
  const int p   = (blk >> 9) & 1;
  const int s0  = (blk & 511) << 6;
  const int si  = tid & 63;
  const int w   = __builtin_amdgcn_readfirstlane(tid >> 6);
  const int g   = (p << 2) + w;

  const float* xb  = x + ((size_t)b << 21);
  const float* xs0 = xb + s0 + si;

  for (int i = tid; i < KK * 64; i += 256) {
    int k  = i >> 6;
    int f  = (k << 15) + s0 + (i & 63);
    int kw = f % 3; int u = f / 3;
    int kh = u % 3; u /= 3;
    int kd = u % 3; u /= 3;
    int ww = (u & 31) + kw - 1; u >>= 5;
    int hh = (u & 31) + kh - 1; u >>= 5;
    int dd = u + kd - 1;
    int off = -1;
    if (((unsigned)ww < 32u) & ((unsigned)hh < 32u) & ((unsigned)dd < 32u))
      off = (dd << 10) + (hh << 5) + ww;
    offs[i] = off;
  }

  {
    float acc[16];
#pragma unroll
    for (int j = 0; j < 16; ++j) acc[j] = 0.f;
#pragma unroll
    for (int half = 0; half < 2; ++half) {
      float xv[32];
#pragma unroll
      for (int c = 0; c < 32; ++c)
        xv[c] = xs0[(size_t)(half * 32 + c) << 15];
      const float* wrw = wr + (w * 16) * CC + half * 32;
#pragma unroll
      for (int j = 0; j < 16; ++j) {
        const float* r0 = wrw + j * CC;
        float a0 = 0.f, a1 = 0.f;
#pragma unroll
        for (int c = 0; c < 32; c += 2) {
          a0 = fmaf(r0[c],     xv[c],     a0);
          a1 = fmaf(r0[c + 1], xv[c + 1], a1);
        }
        acc[j] += a0 + a1;
      }
    }
#pragma unroll
    for (int j = 0; j < 16; ++j) {
      int o = w * 16 + j;
      float v = (acc[j] - mean[o]) * rsqrtf(var[o] + BN_EPS) * gamma[o] + beta[o];
      sv[o * 64 + si] = v > 0.f ? v : 0.f;
    }
  }
  __syncthreads();

  float kreg[27];
#pragma unroll
  for (int j = 0; j < KK; ++j) kreg[j] = 0.f;
#pragma unroll
  for (int e = 0; e < 8; ++e) {
    float xv[8];
#pragma unroll
    for (int c = 0; c < 8; ++c) xv[c] = sv[(e * 8 + c) * 64 + si];
    const float* wsw = wsp + (g * KK) * CC + e * 8;
#pragma unroll
    for (int j = 0; j < KK; ++j) {
      const float* r = wsw + j * CC;
      float a0 = 0.f, a1 = 0.f;
#pragma unroll
      for (int c = 0; c < 8; c += 2) {
        a0 = fmaf(r[c],     xv[c],     a0);
        a1 = fmaf(r[c + 1], xv[c + 1], a1);
      }
      kreg[j] += a0 + a1;
    }
  }

  {
    const int c0 = g << 3;
    const float* xc0 = xb + ((size_t)c0 << 15);
    float oacc[8];
#pragma unroll
    for (int i = 0; i < 8; ++i) oacc[i] = 0.f;
#pragma unroll
    for (int k = 0; k < KK; ++k) {
      int off = offs[(k << 6) + si];
      float kv = kreg[k];
      if (off >= 0) {
#pragma unroll
        for (int c8 = 0; c8 < 8; ++c8)
          oacc[c8] = fmaf(kv, xc0[off + (c8 << 15)], oacc[c8]);
      }
    }
    float* ob = out + (((size_t)b * CC + c0) << 15) + s0 + si;
#pragma unroll
    for (int i = 0; i < 8; ++i) ob[(size_t)i << 15] = oacc[i];
  }
}

extern "C" void kernel_launch(void* const* d_in, const int* in_sizes, int n_in,
                              void* d_out, int out_size, void* d_ws, size_t ws_size,
                              hipStream_t stream) {
  const float* x     = (const float*)d_in[0];
  const float* wr    = (const float*)d_in[1];
  const float* wsp   = (const float*)d_in[2];
  const float* gamma = (const float*)d_in[3];
  const float* beta  = (const float*)d_in[4];
  const float* mean  = (const float*)d_in[5];
  const float* var   = (const float*)d_in[6];
  float* out = (float*)d_out;

  const size_t need = XT_FLOATS * sizeof(float);  // 16.8 MB
  if (ws_size >= need) {
    float* xT = (float*)d_ws;
    xpose_kernel<<<BB * (S_TOT / 64), 256, 0, stream>>>(x, xT);
    invol_fused_xt<<<BB * 2 * (S_TOT / 64), 256, 0, stream>>>(
        xT, wr, wsp, gamma, beta, mean, var, out);
  } else {
    invol_fused<<<BB * 2 * (S_TOT / 64), 256, 0, stream>>>(
        x, wr, wsp, gamma, beta, mean, var, out);
  }
}